// Round 1
// baseline (398.028 us; speedup 1.0000x reference)
//
#include <hip/hip_runtime.h>

#define T_STEPS 100
#define BATCH   512
#define FIN     784
#define O1      100
#define O1P     112   // padded to 16*7 for thread tiling
#define O2      10
#define BM      64    // b-rows per block in K1
#define KC      16    // K-chunk

// ---------------------------------------------------------------------------
// K1: fused C-mean + GEMM  I1T[t][o][b] = sum_f 0.5*(in[b,t,f,0]+in[b,t,f,1]) * W1[f,o]
// f64 accumulation. Grid: (BATCH/BM, T). 256 threads: 16 b-threads x 16 o-threads,
// thread tile 4(b) x 7(o), O padded 100->112 with zero W columns.
// ---------------------------------------------------------------------------
__global__ __launch_bounds__(256) void k1_gemm(const float* __restrict__ in,
                                               const float* __restrict__ W1,
                                               double* __restrict__ I1T) {
  __shared__ double A_lds[KC][BM + 1];   // +1 pad: conflict-free stride-16 reads/writes
  __shared__ double W_lds[KC][O1P];
  const int t   = blockIdx.y;
  const int b0  = blockIdx.x * BM;
  const int tid = threadIdx.x;
  const int bt  = tid & 15;        // 0..15 (b thread)
  const int ot  = tid >> 4;        // 0..15 (o thread)

  // zero the padded W columns once (never rewritten by staging)
  for (int i = tid; i < KC * (O1P - O1); i += 256) {
    int k = i / (O1P - O1), o = O1 + (i - k * (O1P - O1));
    W_lds[k][o] = 0.0;
  }

  double acc[4][7];
#pragma unroll
  for (int m = 0; m < 4; ++m)
#pragma unroll
    for (int n = 0; n < 7; ++n) acc[m][n] = 0.0;

  for (int kc = 0; kc < FIN / KC; ++kc) {
    __syncthreads();  // previous compute done before LDS rewrite
    // stage A: 64 b-rows x 16 k x 2 c = 512 float4 loads (coalesced 128B runs)
#pragma unroll
    for (int p = 0; p < 2; ++p) {
      int q  = p * 256 + tid;
      int bl = q >> 3, fq = q & 7;           // fq -> f-pair
      int f  = kc * KC + fq * 2;
      const float4 v = *reinterpret_cast<const float4*>(
          &in[(((size_t)(b0 + bl) * T_STEPS + t) * FIN + f) * 2]);
      A_lds[fq * 2 + 0][bl] = 0.5 * ((double)v.x + (double)v.y);
      A_lds[fq * 2 + 1][bl] = 0.5 * ((double)v.z + (double)v.w);
    }
    // stage W: 16 x 100 f32, coalesced
    for (int i = tid; i < KC * O1; i += 256) {
      int k = i / O1, o = i - k * O1;
      W_lds[k][o] = (double)W1[(kc * KC + k) * O1 + o];
    }
    __syncthreads();
#pragma unroll
    for (int k = 0; k < KC; ++k) {
      double a[4], w[7];
#pragma unroll
      for (int m = 0; m < 4; ++m) a[m] = A_lds[k][bt + 16 * m];
#pragma unroll
      for (int n = 0; n < 7; ++n) w[n] = W_lds[k][ot + 16 * n];
#pragma unroll
      for (int m = 0; m < 4; ++m)
#pragma unroll
        for (int n = 0; n < 7; ++n) acc[m][n] += a[m] * w[n];
    }
  }
#pragma unroll
  for (int n = 0; n < 7; ++n) {
    int o = ot + 16 * n;
    if (o < O1) {
#pragma unroll
      for (int m = 0; m < 4; ++m) {
        int b = b0 + bt + 16 * m;
        I1T[((size_t)t * O1 + o) * BATCH + b] = acc[m][n];
      }
    }
  }
}

// ---------------------------------------------------------------------------
// K2: BN stats per (t,o) row of I1T: mu, rstd = 1/sqrt(var+eps). One wave per
// row, single global read into registers, f64 shuffle reductions.
// ---------------------------------------------------------------------------
__global__ __launch_bounds__(256) void k2_bnstats(const double* __restrict__ I1T,
                                                  double* __restrict__ mu,
                                                  double* __restrict__ rstd) {
  const int r    = blockIdx.x * 4 + (threadIdx.x >> 6);  // r = t*O1+o
  const int lane = threadIdx.x & 63;
  const double2* row2 = reinterpret_cast<const double2*>(I1T + (size_t)r * BATCH) + lane * 4;
  double v[8];
#pragma unroll
  for (int u = 0; u < 4; ++u) {
    double2 p = row2[u];
    v[2 * u] = p.x; v[2 * u + 1] = p.y;
  }
  double s = 0.0;
#pragma unroll
  for (int u = 0; u < 8; ++u) s += v[u];
#pragma unroll
  for (int m = 32; m >= 1; m >>= 1) s += __shfl_xor(s, m, 64);
  const double mean = s / 512.0;
  double q = 0.0;
#pragma unroll
  for (int u = 0; u < 8; ++u) { double d = v[u] - mean; q += d * d; }
#pragma unroll
  for (int m = 32; m >= 1; m >>= 1) q += __shfl_xor(q, m, 64);
  if (lane == 0) {
    mu[r]   = mean;
    rstd[r] = 1.0 / sqrt(q / 512.0 + 1e-5);
  }
}

// ---------------------------------------------------------------------------
// K3: layer-1 LIF scan. One thread per (b,o); block = o, thread = b.
// Depth-10 prefetch to hide the sequential-load latency (only 800 waves total).
// ---------------------------------------------------------------------------
__global__ __launch_bounds__(512) void k3_lif1(const double* __restrict__ I1T,
                                               const double* __restrict__ mu,
                                               const double* __restrict__ rstd,
                                               const float* __restrict__ scale,
                                               const float* __restrict__ bias,
                                               float* __restrict__ z1T) {
  const int o = blockIdx.x;
  const int b = threadIdx.x;
  const double sc = (double)scale[o], bs = (double)bias[o];
  double v = 0.0;
  for (int tc = 0; tc < T_STEPS; tc += 10) {
    double x[10], muv[10], rsv[10];
#pragma unroll
    for (int u = 0; u < 10; ++u) {
      const int t = tc + u;
      x[u]   = I1T[((size_t)t * O1 + o) * BATCH + b];
      muv[u] = mu[t * O1 + o];
      rsv[u] = rstd[t * O1 + o];
    }
#pragma unroll
    for (int u = 0; u < 10; ++u) {
      const double i = ((x[u] - muv[u]) * rsv[u]) * sc + bs;
      v = 0.95 * v + i;
      const bool z = (v > 1.0);
      z1T[((size_t)(tc + u) * O1 + o) * BATCH + b] = z ? 1.0f : 0.0f;
      if (z) v = 0.0;
    }
  }
}

// ---------------------------------------------------------------------------
// K4: I2[t][j][b] = sum_o z1T[t][o][b] * W2[o][j]. Block per t, thread per b.
// ---------------------------------------------------------------------------
__global__ __launch_bounds__(512) void k4_proj2(const float* __restrict__ z1T,
                                                const float* __restrict__ W2,
                                                double* __restrict__ I2) {
  __shared__ double W2_lds[O1 * O2];
  const int t = blockIdx.x;
  const int b = threadIdx.x;
  for (int i = threadIdx.x; i < O1 * O2; i += 512) W2_lds[i] = (double)W2[i];
  __syncthreads();
  double acc[O2];
#pragma unroll
  for (int j = 0; j < O2; ++j) acc[j] = 0.0;
  for (int o = 0; o < O1; ++o) {
    const double z = (double)z1T[((size_t)t * O1 + o) * BATCH + b];
#pragma unroll
    for (int j = 0; j < O2; ++j) acc[j] += z * W2_lds[o * O2 + j];
  }
#pragma unroll
  for (int j = 0; j < O2; ++j)
    I2[((size_t)t * O2 + j) * BATCH + b] = acc[j];
}

// ---------------------------------------------------------------------------
// K5: layer-2 LIF scan + time-mean. Block per j, thread per b.
// ---------------------------------------------------------------------------
__global__ __launch_bounds__(512) void k5_lif2(const double* __restrict__ I2,
                                               float* __restrict__ out) {
  const int j = blockIdx.x;
  const int b = threadIdx.x;
  double v = 0.0;
  int cnt = 0;
  for (int tc = 0; tc < T_STEPS; tc += 10) {
    double x[10];
#pragma unroll
    for (int u = 0; u < 10; ++u)
      x[u] = I2[((size_t)(tc + u) * O2 + j) * BATCH + b];
#pragma unroll
    for (int u = 0; u < 10; ++u) {
      v = 0.95 * v + x[u];
      if (v > 1.0) { ++cnt; v = 0.0; }
    }
  }
  out[b * O2 + j] = (float)((double)cnt / 100.0);
}

// ---------------------------------------------------------------------------
extern "C" void kernel_launch(void* const* d_in, const int* in_sizes, int n_in,
                              void* d_out, int out_size, void* d_ws, size_t ws_size,
                              hipStream_t stream) {
  const float* in    = (const float*)d_in[0];
  // d_in[1] = trgt (unused by the output)
  const float* W1    = (const float*)d_in[2];
  const float* scale = (const float*)d_in[3];
  const float* bias  = (const float*)d_in[4];
  const float* W2    = (const float*)d_in[5];
  float* out = (float*)d_out;

  char* ws = (char*)d_ws;
  size_t off = 0;
  double* I1T  = (double*)(ws + off); off += (size_t)T_STEPS * O1 * BATCH * sizeof(double); // 40.96 MB
  double* mu   = (double*)(ws + off); off += (size_t)T_STEPS * O1 * sizeof(double);         // 80 KB
  double* rstd = (double*)(ws + off); off += (size_t)T_STEPS * O1 * sizeof(double);         // 80 KB
  float*  z1T  = (float*)(ws + off);  off += (size_t)T_STEPS * O1 * BATCH * sizeof(float);  // 20.48 MB
  double* I2   = (double*)(ws + off); off += (size_t)T_STEPS * O2 * BATCH * sizeof(double); // 4.10 MB

  k1_gemm   <<<dim3(BATCH / BM, T_STEPS), 256, 0, stream>>>(in, W1, I1T);
  k2_bnstats<<<dim3(T_STEPS * O1 / 4),    256, 0, stream>>>(I1T, mu, rstd);
  k3_lif1   <<<dim3(O1),                  512, 0, stream>>>(I1T, mu, rstd, scale, bias, z1T);
  k4_proj2  <<<dim3(T_STEPS),             512, 0, stream>>>(z1T, W2, I2);
  k5_lif2   <<<dim3(O2),                  512, 0, stream>>>(I2, out);
}